// Round 6
// baseline (271.511 us; speedup 1.0000x reference)
//
#include <hip/hip_runtime.h>
#include <hip/hip_bf16.h>
#include <hip/hip_cooperative_groups.h>
#include <math.h>

namespace cg = cooperative_groups;

// Problem constants
#define N_   16
#define A_   64
#define HW_  256
#define B_   32
#define C_   16
#define D_   16

// ws layout (floats)
#define F_POSE 0u          // 32*256*16*16 = 2097152  [b][s][n][pp], BN applied
#define F_WT   2097152u    // 2097152                 [b][s][c*16+mj]
#define F_ACT  4194304u    // 131072                  [b][n][s], BN+sigmoid applied
#define F_PART 4325376u    // 512*33*256 = 4325376
#define F_RED  8650752u    // 8*33*256 = 67584
#define F_P2   8718336u    // 16*4160 = 66560 (x second-moment partials)
#define F_BNP  8784896u    // 128
#define F_MJ   8785024u    // 4096
#define F_IP   8789120u    // 4096
#define F_BASE 8793216u    // 256
#define F_NU   8793472u    // 256
#define F_EPI  8793728u    // 256
#define F_ELAM 8793984u    // 256

__device__ __forceinline__ float digamma_f(float x){
    float r = 0.f;
    while (x < 8.f){ r -= 1.f/x; x += 1.f; }
    float inv = 1.f/x, inv2 = inv*inv;
    float p = logf(x) - 0.5f*inv
            - inv2*(0.08333333333333333f - inv2*(0.008333333333333333f - inv2*0.003968253968253968f));
    return r + p;
}

// ---------------- x statistics: per-n partial M[64][64] and xbar[64] ----------------
__global__ __launch_bounds__(256) void k_xstat(const float* __restrict__ x,
    float* __restrict__ P2)
{
    const int n = blockIdx.x;
    const int t = threadIdx.x;
    const int ai = t>>4, bi = t&15;
    __shared__ float lx[64*33];   // [a][sl pad33], 32-site chunks
    float macc[16];
#pragma unroll
    for (int k=0;k<16;k++) macc[k]=0.f;

    for (int s0=0; s0<256; s0+=32){
        __syncthreads();
        {
            const int a  = t>>2;
            const int sl = (t&3)*8;
            const float* src = x + (size_t)n*16384 + (size_t)a*256 + s0 + sl;
            float4 v0 = ((const float4*)src)[0];
            float4 v1 = ((const float4*)src)[1];
            float* d = lx + a*33 + sl;
            d[0]=v0.x; d[1]=v0.y; d[2]=v0.z; d[3]=v0.w;
            d[4]=v1.x; d[5]=v1.y; d[6]=v1.z; d[7]=v1.w;
        }
        __syncthreads();
        for (int sl=0; sl<32; ++sl){
            float av[4], bv[4];
#pragma unroll
            for (int i=0;i<4;i++){
                av[i] = lx[(ai*4+i)*33+sl];
                bv[i] = lx[(bi*4+i)*33+sl];
            }
#pragma unroll
            for (int i=0;i<4;i++)
#pragma unroll
                for (int j=0;j<4;j++)
                    macc[i*4+j] = fmaf(av[i], bv[j], macc[i*4+j]);
        }
    }
#pragma unroll
    for (int i=0;i<4;i++)
#pragma unroll
        for (int j=0;j<4;j++)
            P2[(size_t)n*4160 + (ai*4+i)*64 + (bi*4+j)] = macc[i*4+j];
    if (t < 64){
        float s = 0.f;
        const float* xr = x + (size_t)n*16384 + (size_t)t*256;
        for (int k=0;k<256;k++) s += xr[k];
        P2[(size_t)n*4160 + 4096 + t] = s;
    }
}

// ---------------- BN params from x-moments (analytic) ----------------
__global__ __launch_bounds__(256) void k_bnw(const float* __restrict__ P2,
    const float* __restrict__ pw, const float* __restrict__ gp,
    const float* __restrict__ bp, const float* __restrict__ ga,
    const float* __restrict__ bbeta, float* __restrict__ bnp)
{
    const int bid = blockIdx.x;   // 0,1: pose outputs; 2: acts
    const int t = threadIdx.x;
    __shared__ float M[4160];
    for (int e=t; e<4160; e+=256){
        float a = 0.f;
        for (int nn=0; nn<16; ++nn) a += P2[(size_t)nn*4160 + e];
        M[e] = a * (1.f/4096.f);
    }
    __syncthreads();

    if (bid < 2){
        const int o = bid*256 + t;
        float wv[64];
        const float4* wr = (const float4*)(pw + (size_t)o*64);
#pragma unroll
        for (int i=0;i<16;i++){
            float4 v = wr[i];
            wv[i*4+0]=v.x; wv[i*4+1]=v.y; wv[i*4+2]=v.z; wv[i*4+3]=v.w;
        }
        float mean = 0.f;
#pragma unroll
        for (int a=0;a<64;a++) mean = fmaf(wv[a], M[4096+a], mean);
        float q = 0.f;
#pragma unroll
        for (int a=0;a<64;a++){
            float inner = 0.f;
#pragma unroll
            for (int b2=0;b2<64;b2++) inner = fmaf(wv[b2], M[a*64+b2], inner);
            q = fmaf(wv[a], inner, q);
        }
        float gm = mean, gq = q;
#pragma unroll
        for (int off=8; off>=1; off>>=1){
            gm += __shfl_xor(gm, off, 16);
            gq += __shfl_xor(gq, off, 16);
        }
        gm *= 0.0625f; gq *= 0.0625f;
        if ((t&15)==0){
            const int b = bid*16 + (t>>4);
            float var = gq - gm*gm;
            float rs = rsqrtf(var + 1e-5f);
            float sc = gp[b]*rs;
            bnp[b] = sc; bnp[32+b] = bp[b] - gm*sc;
        }
    } else {
        const int j = t>>3, part = t&7, a0 = part*8;
        float wv[64];
        const float4* wr = (const float4*)(pw + (size_t)(512+j)*64);
#pragma unroll
        for (int i=0;i<16;i++){
            float4 v = wr[i];
            wv[i*4+0]=v.x; wv[i*4+1]=v.y; wv[i*4+2]=v.z; wv[i*4+3]=v.w;
        }
        float mean = 0.f, q = 0.f;
#pragma unroll
        for (int i=0;i<8;i++){
            const int a = a0+i;
            mean = fmaf(wv[a], M[4096+a], mean);
            float inner = 0.f;
#pragma unroll
            for (int b2=0;b2<64;b2++) inner = fmaf(wv[b2], M[a*64+b2], inner);
            q = fmaf(wv[a], inner, q);
        }
#pragma unroll
        for (int off=4; off>=1; off>>=1){
            mean += __shfl_xor(mean, off, 8);
            q    += __shfl_xor(q,    off, 8);
        }
        if (part==0){
            float var = q - mean*mean;
            float rs = rsqrtf(var + 1e-5f);
            float sc = ga[j]*rs;
            bnp[64+j] = sc; bnp[96+j] = bbeta[j] - mean*sc;
        }
    }
}

// ---------------- conv 1x1 with BN(+sigmoid) folded, transposed outputs ----------------
__global__ __launch_bounds__(256) void k_conv2(const float* __restrict__ x,
    const float* __restrict__ pw, const float* __restrict__ bnp,
    float* __restrict__ POSE, float* __restrict__ ACT)
{
    const int g = blockIdx.x;      // 0..33
    const int n = blockIdx.y;
    const int t = threadIdx.x;     // site
    __shared__ float swl[1024];
    ((float4*)swl)[t] = ((const float4*)(pw + (size_t)g*1024))[t];
    __syncthreads();
    const float* xp = x + (size_t)n*16384 + t;
    float acc[16];
#pragma unroll
    for (int i=0;i<16;i++) acc[i]=0.f;
#pragma unroll 4
    for (int a=0;a<A_;a++){
        float xv = xp[(size_t)a*256];
#pragma unroll
        for (int oo=0;oo<16;oo++) acc[oo] = fmaf(xv, swl[oo*64+a], acc[oo]);
    }
    if (g < 32){
        const int b = g;
        const float sc = bnp[b], sh = bnp[32+b];
        float* dst = POSE + (size_t)b*65536 + (size_t)t*256 + n*16;
#pragma unroll
        for (int i=0;i<4;i++){
            float4 v;
            v.x = fmaf(acc[i*4+0], sc, sh);
            v.y = fmaf(acc[i*4+1], sc, sh);
            v.z = fmaf(acc[i*4+2], sc, sh);
            v.w = fmaf(acc[i*4+3], sc, sh);
            *(float4*)(dst + i*4) = v;
        }
    } else {
#pragma unroll
        for (int oo=0;oo<16;oo++){
            const int ba_ = (g-32)*16 + oo;
            float y = fmaf(acc[oo], bnp[64+ba_], bnp[96+ba_]);
            y = 1.f/(1.f+expf(-y));
            ACT[(size_t)ba_*4096 + (size_t)n*256 + t] = y;
        }
    }
}

// ---------------- W_ij transpose: [b][cmj][s] -> [b][s][cmj] ----------------
__global__ __launch_bounds__(256) void k_wt(const float* __restrict__ W,
    float* __restrict__ WTo)
{
    const int b = blockIdx.x, chunk = blockIdx.y;
    const int s0 = chunk*16;
    const int t = threadIdx.x;    // cmj row
    __shared__ float lw[16*256];
    const float* src = W + ((size_t)b*256 + t)*256 + s0;
    float4 v0 = ((const float4*)src)[0];
    float4 v1 = ((const float4*)src)[1];
    float4 v2 = ((const float4*)src)[2];
    float4 v3 = ((const float4*)src)[3];
    lw[ 0*256+t]=v0.x; lw[ 1*256+t]=v0.y; lw[ 2*256+t]=v0.z; lw[ 3*256+t]=v0.w;
    lw[ 4*256+t]=v1.x; lw[ 5*256+t]=v1.y; lw[ 6*256+t]=v1.z; lw[ 7*256+t]=v1.w;
    lw[ 8*256+t]=v2.x; lw[ 9*256+t]=v2.y; lw[10*256+t]=v2.z; lw[11*256+t]=v2.w;
    lw[12*256+t]=v3.x; lw[13*256+t]=v3.y; lw[14*256+t]=v3.z; lw[15*256+t]=v3.w;
    __syncthreads();
    float* dst = WTo + ((size_t)b*256 + s0)*256;
#pragma unroll
    for (int j=0;j<4;j++){
        int flat = j*1024 + t*4;
        *(float4*)(dst + flat) = *(const float4*)(lw + flat);
    }
}

// ================= phase bodies (shared by coop kernel and fallback) =================

__device__ __forceinline__ void pass_phase(int wg, int it,
    const float* __restrict__ POSE, const float* __restrict__ ACT,
    const float* __restrict__ WT,
    const float* __restrict__ mjG, const float* __restrict__ ipG,
    const float* __restrict__ baseG, const float* __restrict__ nuG,
    float* __restrict__ Part, float* sh)
{
    const int chunk = wg & 15, b = wg >> 4;
    const int s0 = chunk*16;
    const int t = threadIdx.x;
    const int n = t>>4, c = t&15;
    float* shP = sh;           // [si][n][pad20]
    float* shW = sh + 5120;    // [si][c][pad20]
    float* shA = sh + 10240;   // [si*16+n]

    const float* psrc = POSE + ((size_t)b*256 + s0)*256;
    const float* wsrc = WT   + ((size_t)b*256 + s0)*256;
#pragma unroll
    for (int j=0;j<4;j++){
        int flat = j*1024 + t*4;
        int si = flat>>8, rm = flat&255;
        int nn = rm>>4, p0 = rm&15;
        *(float4*)(shP + si*320 + nn*20 + p0) = *(const float4*)(psrc+flat);
        *(float4*)(shW + si*320 + nn*20 + p0) = *(const float4*)(wsrc+flat);
    }
    if (t < 64){
        int nn = t>>2, s4 = (t&3)*4;
        float4 v = *(const float4*)(ACT + (size_t)b*4096 + nn*256 + s0 + s4);
        shA[(s4+0)*16+nn] = v.x;
        shA[(s4+1)*16+nn] = v.y;
        shA[(s4+2)*16+nn] = v.z;
        shA[(s4+3)*16+nn] = v.w;
    }

    float mj[16], ip[16], basev=0.f, nuv=0.f;
    if (it){
#pragma unroll
        for (int d=0; d<16; d+=4){
            float4 v = *(const float4*)(mjG + (size_t)t*16 + d);
            mj[d]=v.x; mj[d+1]=v.y; mj[d+2]=v.z; mj[d+3]=v.w;
            float4 u = *(const float4*)(ipG + (size_t)t*16 + d);
            ip[d]=u.x; ip[d+1]=u.y; ip[d+2]=u.z; ip[d+3]=u.w;
        }
        basev = baseG[t]; nuv = nuG[t];
    }
    __syncthreads();

    float racc=0.f, s1[16], s2[16];
#pragma unroll
    for (int d=0;d<16;d++){ s1[d]=0.f; s2[d]=0.f; }

    for (int si=0; si<16; ++si){
        float P[16], Wv[16];
        const float* pb = shP + si*320 + n*20;
        const float* wb = shW + si*320 + c*20;
#pragma unroll
        for (int i=0;i<16;i+=4){
            float4 v = *(const float4*)(pb+i);
            P[i]=v.x; P[i+1]=v.y; P[i+2]=v.z; P[i+3]=v.w;
            float4 u = *(const float4*)(wb+i);
            Wv[i]=u.x; Wv[i+1]=u.y; Wv[i+2]=u.z; Wv[i+3]=u.w;
        }
        float V[16];
#pragma unroll
        for (int a=0;a<4;a++){
#pragma unroll
            for (int j=0;j<4;j++){
                float acc = P[a*4+0]*Wv[0*4+j];
                acc = fmaf(P[a*4+1], Wv[1*4+j], acc);
                acc = fmaf(P[a*4+2], Wv[2*4+j], acc);
                acc = fmaf(P[a*4+3], Wv[3*4+j], acc);
                V[a*4+j] = acc;
            }
        }
        const float av = shA[si*16+n];
        float r;
        if (it == 0){
            r = 0.0625f * av;
        } else {
            float q = 0.f;
#pragma unroll
            for (int d=0;d<16;d++){
                float dv = V[d]-mj[d];
                q = fmaf(dv*ip[d], dv, q);
            }
            float arg = fmaf(-0.5f*nuv, q, basev);
            float mx = arg;
#pragma unroll
            for (int off=8; off>=1; off>>=1) mx = fmaxf(mx, __shfl_xor(mx, off, 64));
            float e = expf(arg-mx);
            float ssum = e;
#pragma unroll
            for (int off=8; off>=1; off>>=1) ssum += __shfl_xor(ssum, off, 64);
            r = (e/ssum)*av;
        }
        racc += r;
#pragma unroll
        for (int d=0;d<16;d++){
            s1[d] = fmaf(r, V[d], s1[d]);
            s2[d] = fmaf(r*V[d], V[d], s2[d]);
        }
    }

    float* pp = Part + ((size_t)wg*33)*256 + t;
    pp[0] = racc;
#pragma unroll
    for (int d=0;d<16;d++){
        pp[(size_t)(1+d)*256]  = s1[d];
        pp[(size_t)(17+d)*256] = s2[d];
    }
}

__device__ __forceinline__ void reduce_phase(int wg,
    const float* __restrict__ Part, float* __restrict__ Red)
{
    const int k = wg>>3;      // 0..32
    const int q = wg&7;       // 0..7
    const int t = threadIdx.x;
    const size_t STR = 33u*256u;
    const float* src = Part + (size_t)q*64u*STR + (size_t)k*256u + t;
    float a0=0,a1=0,a2=0,a3=0,a4=0,a5=0,a6=0,a7=0;
#pragma unroll
    for (int i=0;i<64;i+=8){
        a0 += src[(size_t)(i+0)*STR];
        a1 += src[(size_t)(i+1)*STR];
        a2 += src[(size_t)(i+2)*STR];
        a3 += src[(size_t)(i+3)*STR];
        a4 += src[(size_t)(i+4)*STR];
        a5 += src[(size_t)(i+5)*STR];
        a6 += src[(size_t)(i+6)*STR];
        a7 += src[(size_t)(i+7)*STR];
    }
    Red[((size_t)q*33 + k)*256 + t] = ((a0+a1)+(a2+a3)) + ((a4+a5)+(a6+a7));
}

__device__ __forceinline__ void derive_phase(const float* __restrict__ Red,
    float* __restrict__ mjG, float* __restrict__ ipG, float* __restrict__ baseG,
    float* __restrict__ nuG, float* __restrict__ EpiG, float* __restrict__ ElamG)
{
    const int t = threadIdx.x;
    float M[33];
#pragma unroll
    for (int k=0;k<33;k++) M[k]=0.f;
    for (int q=0; q<8; q++){
        const float* rp = Red + (size_t)q*33u*256u + t;
#pragma unroll
        for (int k=0;k<33;k++) M[k] += rp[(size_t)k*256u];
    }
    float Rj  = M[0];
    float kap = 1.f + Rj;
    float nu  = 17.f + Rj;
    float ik  = 1.f/kap;
    float lndet = 0.f;
#pragma unroll
    for (int d=0; d<16; d++){
        float S1 = M[1+d], S2 = M[17+d];
        float m    = S1*ik;
        float iPsi = 1.f + S2 - S1*S1*ik;
        mjG[(size_t)t*16+d] = m;
        ipG[(size_t)t*16+d] = 1.f/iPsi;
        lndet -= logf(iPsi);
    }
    float El = lndet + 11.090354888959125f;
#pragma unroll
    for (int d=0; d<16; d++) El += digamma_f(0.5f*(nu - (float)d));
    float asum = kap;
#pragma unroll
    for (int off=8; off>=1; off>>=1) asum += __shfl_xor(asum, off, 64);
    float Epi = digamma_f(kap) - digamma_f(asum);
    nuG[t]   = nu;
    EpiG[t]  = Epi;
    ElamG[t] = El;
    baseG[t] = Epi + 0.5f*El - 14.703016531274762f - 8.f*ik;
}

__device__ __forceinline__ void final_phase(int c,
    const float* __restrict__ mjG, const float* __restrict__ EpiG,
    const float* __restrict__ ElamG, const float* __restrict__ bu,
    const float* __restrict__ ba, float* __restrict__ out, float* red)
{
    const int t = threadIdx.x;
    const int n = t>>4, d = t&15;
    float mv = mjG[(size_t)(n*16+c)*16 + d];
    float s = mv, q = mv*mv;
#pragma unroll
    for (int off=32; off>=1; off>>=1){
        s += __shfl_xor(s, off, 64);
        q += __shfl_xor(q, off, 64);
    }
    if ((t&63)==0){ red[t>>6]=s; red[4+(t>>6)]=q; }
    __syncthreads();
    float S = red[0]+red[1]+red[2]+red[3];
    float Q = red[4]+red[5]+red[6]+red[7];
    float mean = S*(1.f/256.f);
    float var  = Q*(1.f/256.f) - mean*mean;
    float rs   = rsqrtf(var + 1e-5f);
    out[256 + (size_t)(n*16+c)*16 + d] = (mv-mean)*rs;

    if (t < 16){
        const int nn = t;
        float Ep = EpiG[nn*16+c], El = ElamG[nn*16+c];
        float Hq = 22.703016531274762f - 0.5f*El;
        float araw = ba[c] - (expf(Ep)*Hq + bu[c]);
        float as = araw, aq = araw*araw;
        // reduce over 16 n-lanes: width 16 so off=8 exchanges halves
        // (width 8 + off 8 returns own value -> doubled half-sums; R4 bug)
#pragma unroll
        for (int off=8; off>=1; off>>=1){
            as += __shfl_xor(as, off, 16);
            aq += __shfl_xor(aq, off, 16);
        }
        float am  = as*(1.f/16.f);
        float av  = aq*(1.f/16.f) - am*am;
        float ars = rsqrtf(av + 1e-5f);
        float z = (araw-am)*ars;
        out[nn*16+c] = 1.f/(1.f+expf(-z));
    }
}

// ================= cooperative mega-kernel =================
__global__ __launch_bounds__(256) void k_em(
    const float* __restrict__ POSE, const float* __restrict__ ACT,
    const float* __restrict__ WT, float* __restrict__ Part,
    float* __restrict__ Red, float* __restrict__ mjG, float* __restrict__ ipG,
    float* __restrict__ baseG, float* __restrict__ nuG,
    float* __restrict__ EpiG, float* __restrict__ ElamG,
    const float* __restrict__ bu, const float* __restrict__ ba,
    float* __restrict__ out)
{
    __shared__ float sh[10496];
    cg::grid_group grid = cg::this_grid();
    const int wg = blockIdx.x;
    for (int it=0; it<3; ++it){
        pass_phase(wg, it, POSE, ACT, WT, mjG, ipG, baseG, nuG, Part, sh);
        grid.sync();
        if (wg < 264) reduce_phase(wg, Part, Red);
        grid.sync();
        if (wg == 0) derive_phase(Red, mjG, ipG, baseG, nuG, EpiG, ElamG);
        grid.sync();
    }
    if (wg < 16) final_phase(wg, mjG, EpiG, ElamG, bu, ba, out, sh);
}

// ================= fallback standalone kernels =================
__global__ __launch_bounds__(256) void k_fpass(int it,
    const float* __restrict__ POSE, const float* __restrict__ ACT,
    const float* __restrict__ WT, const float* __restrict__ mjG,
    const float* __restrict__ ipG, const float* __restrict__ baseG,
    const float* __restrict__ nuG, float* __restrict__ Part)
{
    __shared__ float sh[10496];
    pass_phase(blockIdx.x, it, POSE, ACT, WT, mjG, ipG, baseG, nuG, Part, sh);
}
__global__ __launch_bounds__(256) void k_freduce(const float* __restrict__ Part,
    float* __restrict__ Red)
{
    reduce_phase(blockIdx.x, Part, Red);
}
__global__ __launch_bounds__(256) void k_fderive(const float* __restrict__ Red,
    float* __restrict__ mjG, float* __restrict__ ipG, float* __restrict__ baseG,
    float* __restrict__ nuG, float* __restrict__ EpiG, float* __restrict__ ElamG)
{
    derive_phase(Red, mjG, ipG, baseG, nuG, EpiG, ElamG);
}
__global__ __launch_bounds__(256) void k_ffinal(const float* __restrict__ mjG,
    const float* __restrict__ EpiG, const float* __restrict__ ElamG,
    const float* __restrict__ bu, const float* __restrict__ ba,
    float* __restrict__ out)
{
    __shared__ float red[8];
    final_phase(blockIdx.x, mjG, EpiG, ElamG, bu, ba, out, red);
}

extern "C" void kernel_launch(void* const* d_in, const int* in_sizes, int n_in,
                              void* d_out, int out_size, void* d_ws, size_t ws_size,
                              hipStream_t stream)
{
    const float* x   = (const float*)d_in[0];
    const float* pw  = (const float*)d_in[1];
    const float* gp  = (const float*)d_in[2];
    const float* bp  = (const float*)d_in[3];
    const float* ga  = (const float*)d_in[4];
    const float* bb  = (const float*)d_in[5];
    const float* Wij = (const float*)d_in[6];
    const float* bu  = (const float*)d_in[7];
    const float* ba  = (const float*)d_in[8];
    float* out = (float*)d_out;
    float* ws  = (float*)d_ws;

    float* POSE = ws + F_POSE;
    float* WT   = ws + F_WT;
    float* ACT  = ws + F_ACT;
    float* Part = ws + F_PART;
    float* Red  = ws + F_RED;
    float* P2   = ws + F_P2;
    float* bnp  = ws + F_BNP;
    float* mj   = ws + F_MJ;
    float* ip   = ws + F_IP;
    float* base = ws + F_BASE;
    float* nu   = ws + F_NU;
    float* Epi  = ws + F_EPI;
    float* Elam = ws + F_ELAM;

    k_xstat<<<16, 256, 0, stream>>>(x, P2);
    k_bnw<<<3, 256, 0, stream>>>(P2, pw, gp, bp, ga, bb, bnp);
    k_conv2<<<dim3(34,16), 256, 0, stream>>>(x, pw, bnp, POSE, ACT);
    k_wt<<<dim3(32,16), 256, 0, stream>>>(Wij, WT);

    // Decide coop-vs-fallback via HOST-side queries only (deterministic per
    // device; never issues a failable launch into a capturing stream).
    int dev = 0;
    hipGetDevice(&dev);
    hipDeviceProp_t props;
    hipGetDeviceProperties(&props, dev);
    int maxBlk = 0;
    hipOccupancyMaxActiveBlocksPerMultiprocessor(&maxBlk, (const void*)k_em, 256, 0);
    bool coop_ok = props.cooperativeLaunch &&
                   ((long)maxBlk * props.multiProcessorCount >= 512);

    bool done = false;
    if (coop_ok){
        void* args[] = { (void*)&POSE, (void*)&ACT, (void*)&WT, (void*)&Part,
                         (void*)&Red, (void*)&mj, (void*)&ip, (void*)&base,
                         (void*)&nu, (void*)&Epi, (void*)&Elam,
                         (void*)&bu, (void*)&ba, (void*)&out };
        hipError_t e = hipLaunchCooperativeKernel((void*)k_em, dim3(512), dim3(256),
                                                  args, 0, stream);
        done = (e == hipSuccess);
    }
    if (!done){
        // fallback: separate launches (identical math)
        for (int it=0; it<3; ++it){
            k_fpass<<<512, 256, 0, stream>>>(it, POSE, ACT, WT, mj, ip, base, nu, Part);
            k_freduce<<<264, 256, 0, stream>>>(Part, Red);
            k_fderive<<<1, 256, 0, stream>>>(Red, mj, ip, base, nu, Epi, Elam);
        }
        k_ffinal<<<16, 256, 0, stream>>>(mj, Epi, Elam, bu, ba, out);
    }
}

// Round 7
// 257.226 us; speedup vs baseline: 1.0555x; 1.0555x over previous
//
#include <hip/hip_runtime.h>
#include <hip/hip_bf16.h>
#include <math.h>

// Problem constants
#define N_   16
#define A_   64
#define HW_  256
#define B_   32
#define C_   16
#define D_   16

// ws layout (floats) — ~34.6 MB total
#define F_POSE  0u          // 2097152  POSEraw [b][s][n][pp]  (raw conv out, transposed)
#define F_WT    2097152u    // 2097152  WT [b][s][c*16+mj]
#define F_ACT   4194304u    // 131072   ACTraw [ch=b][n][s]    (raw conv out)
#define F_PART  4325376u    // 4325376  Part[512][33][256]
#define F_RED   8650752u    // 8448     Red[33][256]
#define F_STATP 8659200u    // 1024     per-(b,n) pose sum/sumsq
#define F_STATA 8660224u    // 1024     per-(ch,n) act sum/sumsq
#define F_BNP   8661248u    // 128      {pose sc, pose sh, act sc, act sh}

__device__ __forceinline__ float digamma_f(float x){
    // valid for x >= ~1 (all call sites); shift to x>=8 then asymptotic
    float r = 0.f;
    while (x < 8.f){ r -= 1.f/x; x += 1.f; }
    float inv = 1.f/x, inv2 = inv*inv;
    float p = logf(x) - 0.5f*inv
            - inv2*(0.08333333333333333f - inv2*(0.008333333333333333f - inv2*0.003968253968253968f));
    return r + p;
}

__device__ __forceinline__ float sigmoid_f(float x){ return 1.f/(1.f+expf(-x)); }

// ---------------- K1: conv 1x1 (raw, transposed out, + BN stat partials) fused with W transpose ----
// blocks 0..543: conv (g = blk%34, n = blk/34); blocks 544..1055: W transpose.
__global__ __launch_bounds__(256) void k_main(const float* __restrict__ x,
    const float* __restrict__ pw, const float* __restrict__ W,
    float* __restrict__ POSEraw, float* __restrict__ ACTraw, float* __restrict__ WTo,
    float* __restrict__ StatP, float* __restrict__ StatA)
{
    __shared__ float sh[4096];
    const int blk = blockIdx.x;
    const int t = threadIdx.x;
    if (blk < 544){
        const int g = blk % 34, n = blk / 34;
        float* swl = sh;                 // 1024 floats of weights
        ((float4*)swl)[t] = ((const float4*)(pw + (size_t)g*1024))[t];
        __syncthreads();
        const float* xp = x + (size_t)n*16384 + t;
        float acc[16];
#pragma unroll
        for (int i=0;i<16;i++) acc[i]=0.f;
#pragma unroll 4
        for (int a=0;a<A_;a++){
            float xv = xp[(size_t)a*256];
#pragma unroll
            for (int oo=0;oo<16;oo++) acc[oo] = fmaf(xv, swl[oo*64+a], acc[oo]);
        }
        if (g < 32){
            // raw transposed store: POSEraw[b][s][n][pp]
            float* dst = POSEraw + (size_t)g*65536 + (size_t)t*256 + n*16;
#pragma unroll
            for (int i=0;i<4;i++){
                float4 v; v.x=acc[i*4+0]; v.y=acc[i*4+1]; v.z=acc[i*4+2]; v.w=acc[i*4+3];
                *(float4*)(dst + i*4) = v;
            }
            // per-(b,n) partial stats over 16 pp x 256 sites
            float sp=0.f, sq=0.f;
#pragma unroll
            for (int oo=0;oo<16;oo++){ sp += acc[oo]; sq = fmaf(acc[oo], acc[oo], sq); }
#pragma unroll
            for (int off=32; off>=1; off>>=1){
                sp += __shfl_xor(sp, off, 64);
                sq += __shfl_xor(sq, off, 64);
            }
            float* red = sh + 1024;
            if ((t&63)==0){ red[t>>6]=sp; red[4+(t>>6)]=sq; }
            __syncthreads();
            if (t==0){
                StatP[(size_t)(g*16+n)*2  ] = red[0]+red[1]+red[2]+red[3];
                StatP[(size_t)(g*16+n)*2+1] = red[4]+red[5]+red[6]+red[7];
            }
        } else {
            // raw act store: ACTraw[ch][n][s]
#pragma unroll
            for (int oo=0;oo<16;oo++){
                const int ch = (g-32)*16 + oo;
                ACTraw[(size_t)ch*4096 + (size_t)n*256 + t] = acc[oo];
            }
            // per-(ch,n) partial stats over 256 sites
            float* ared = sh + 1024;     // [16 ch][8]
            const int wid = t>>6;
#pragma unroll
            for (int oo=0;oo<16;oo++){
                float s = acc[oo], q = acc[oo]*acc[oo];
#pragma unroll
                for (int off=32; off>=1; off>>=1){
                    s += __shfl_xor(s, off, 64);
                    q += __shfl_xor(q, off, 64);
                }
                if ((t&63)==0){ ared[oo*8+wid]=s; ared[oo*8+4+wid]=q; }
            }
            __syncthreads();
            if (t<16){
                const int ch = (g-32)*16 + t;
                StatA[(size_t)(ch*16+n)*2  ] = ared[t*8+0]+ared[t*8+1]+ared[t*8+2]+ared[t*8+3];
                StatA[(size_t)(ch*16+n)*2+1] = ared[t*8+4]+ared[t*8+5]+ared[t*8+6]+ared[t*8+7];
            }
        }
    } else {
        // W transpose: [b][cmj][s] -> [b][s][cmj]
        const int q = blk - 544;
        const int b = q & 31, chunk = q >> 5;
        const int s0 = chunk*16;
        float* lw = sh;                  // 4096 floats
        const float* src = W + ((size_t)b*256 + t)*256 + s0;
        float4 v0 = ((const float4*)src)[0];
        float4 v1 = ((const float4*)src)[1];
        float4 v2 = ((const float4*)src)[2];
        float4 v3 = ((const float4*)src)[3];
        lw[ 0*256+t]=v0.x; lw[ 1*256+t]=v0.y; lw[ 2*256+t]=v0.z; lw[ 3*256+t]=v0.w;
        lw[ 4*256+t]=v1.x; lw[ 5*256+t]=v1.y; lw[ 6*256+t]=v1.z; lw[ 7*256+t]=v1.w;
        lw[ 8*256+t]=v2.x; lw[ 9*256+t]=v2.y; lw[10*256+t]=v2.z; lw[11*256+t]=v2.w;
        lw[12*256+t]=v3.x; lw[13*256+t]=v3.y; lw[14*256+t]=v3.z; lw[15*256+t]=v3.w;
        __syncthreads();
        float* dst = WTo + ((size_t)b*256 + s0)*256;
#pragma unroll
        for (int j=0;j<4;j++){
            int flat = j*1024 + t*4;
            *(float4*)(dst + flat) = *(const float4*)(lw + flat);
        }
    }
}

// ---------------- K2: finalize BN params (1 block, 64 threads) ----------------
__global__ __launch_bounds__(64) void k_bnfin(const float* __restrict__ StatP,
    const float* __restrict__ StatA, const float* __restrict__ gp,
    const float* __restrict__ bp, const float* __restrict__ ga,
    const float* __restrict__ bb, float* __restrict__ bnp)
{
    const int t = threadIdx.x;
    if (t < 32){
        float S=0.f, Q=0.f;
        for (int n=0;n<16;n++){ S += StatP[(size_t)(t*16+n)*2]; Q += StatP[(size_t)(t*16+n)*2+1]; }
        float mean = S*(1.f/65536.f), var = Q*(1.f/65536.f) - mean*mean;
        float sc = gp[t]*rsqrtf(var + 1e-5f);
        bnp[t] = sc; bnp[32+t] = bp[t] - mean*sc;
    } else {
        const int ch = t-32;
        float S=0.f, Q=0.f;
        for (int n=0;n<16;n++){ S += StatA[(size_t)(ch*16+n)*2]; Q += StatA[(size_t)(ch*16+n)*2+1]; }
        float mean = S*(1.f/4096.f), var = Q*(1.f/4096.f) - mean*mean;
        float sc = ga[ch]*rsqrtf(var + 1e-5f);
        bnp[64+ch] = sc; bnp[96+ch] = bb[ch] - mean*sc;
    }
}

// ---------------- pass: E-step + moments; derive INLINED per-thread (it>0) ----------------
// grid 512 = (b,chunk); 256 threads = (n,c) = cell t. FIRST=1: R=1/C.
template<int FIRST>
__global__ __launch_bounds__(256) void k_pass(const float* __restrict__ POSEraw,
    const float* __restrict__ ACTraw, const float* __restrict__ WT,
    const float* __restrict__ bnp, const float* __restrict__ RedG,
    float* __restrict__ Part)
{
    const int wg = blockIdx.x;
    const int chunk = wg & 15, b = wg >> 4;
    const int s0 = chunk*16;
    const int t = threadIdx.x;
    const int n = t>>4, c = t&15;
    __shared__ float sh[10496];
    float* shP = sh;           // [si][n][pad20]  BN-applied poses
    float* shW = sh + 5120;    // [si][c][pad20]
    float* shA = sh + 10240;   // [si*16+n]       sigmoided acts

    {
        const float sc = bnp[b], shf = bnp[32+b];
        const float* psrc = POSEraw + ((size_t)b*256 + s0)*256;
        const float* wsrc = WT      + ((size_t)b*256 + s0)*256;
#pragma unroll
        for (int j=0;j<4;j++){
            int flat = j*1024 + t*4;
            int si = flat>>8, rm = flat&255;
            int nn = rm>>4, p0 = rm&15;
            float4 v = *(const float4*)(psrc+flat);
            v.x = fmaf(v.x, sc, shf); v.y = fmaf(v.y, sc, shf);
            v.z = fmaf(v.z, sc, shf); v.w = fmaf(v.w, sc, shf);
            *(float4*)(shP + si*320 + nn*20 + p0) = v;
            *(float4*)(shW + si*320 + nn*20 + p0) = *(const float4*)(wsrc+flat);
        }
        if (t < 64){
            const float sa = bnp[64+b], ha = bnp[96+b];
            int nn = t>>2, s4 = (t&3)*4;
            float4 v = *(const float4*)(ACTraw + (size_t)b*4096 + nn*256 + s0 + s4);
            shA[(s4+0)*16+nn] = sigmoid_f(fmaf(v.x,sa,ha));
            shA[(s4+1)*16+nn] = sigmoid_f(fmaf(v.y,sa,ha));
            shA[(s4+2)*16+nn] = sigmoid_f(fmaf(v.z,sa,ha));
            shA[(s4+3)*16+nn] = sigmoid_f(fmaf(v.w,sa,ha));
        }
    }

    // inline derive of this thread's (n,c) cell from fully-reduced Red[33][256]
    float mj[16], ip[16], basev=0.f, nuv=0.f;
    if (!FIRST){
        const float* rp = RedG + t;
        float Rj  = rp[0];
        float kap = 1.f + Rj;
        nuv = 17.f + Rj;
        float ik  = 1.f/kap;
        float El  = 11.090354888959125f;   // D*ln2
#pragma unroll
        for (int d=0; d<16; d++){
            float S1 = rp[(size_t)(1+d)*256];
            float S2 = rp[(size_t)(17+d)*256];
            mj[d] = S1*ik;
            float iPsi = 1.f + S2 - S1*S1*ik;
            ip[d] = 1.f/iPsi;
            El -= logf(iPsi);
        }
#pragma unroll
        for (int d=0; d<16; d++) El += digamma_f(0.5f*(nuv - (float)d));
        float asum = kap;
#pragma unroll
        for (int off=8; off>=1; off>>=1) asum += __shfl_xor(asum, off, 16);
        float Epi = digamma_f(kap) - digamma_f(asum);
        basev = Epi + 0.5f*El - 14.703016531274762f - 8.f*ik;
    }
    __syncthreads();

    float racc=0.f, s1[16], s2[16];
#pragma unroll
    for (int d=0;d<16;d++){ s1[d]=0.f; s2[d]=0.f; }

    for (int si=0; si<16; ++si){
        float P[16], Wv[16];
        const float* pb = shP + si*320 + n*20;
        const float* wb = shW + si*320 + c*20;
#pragma unroll
        for (int i=0;i<16;i+=4){
            float4 v = *(const float4*)(pb+i);
            P[i]=v.x; P[i+1]=v.y; P[i+2]=v.z; P[i+3]=v.w;
            float4 u = *(const float4*)(wb+i);
            Wv[i]=u.x; Wv[i+1]=u.y; Wv[i+2]=u.z; Wv[i+3]=u.w;
        }
        float V[16];
#pragma unroll
        for (int a=0;a<4;a++){
#pragma unroll
            for (int j=0;j<4;j++){
                float acc = P[a*4+0]*Wv[0*4+j];
                acc = fmaf(P[a*4+1], Wv[1*4+j], acc);
                acc = fmaf(P[a*4+2], Wv[2*4+j], acc);
                acc = fmaf(P[a*4+3], Wv[3*4+j], acc);
                V[a*4+j] = acc;
            }
        }
        const float av = shA[si*16+n];
        float r;
        if (FIRST){
            r = 0.0625f * av;
        } else {
            float q = 0.f;
#pragma unroll
            for (int d=0;d<16;d++){
                float dv = V[d]-mj[d];
                q = fmaf(dv*ip[d], dv, q);
            }
            float arg = fmaf(-0.5f*nuv, q, basev);
            float mx = arg;
#pragma unroll
            for (int off=8; off>=1; off>>=1) mx = fmaxf(mx, __shfl_xor(mx, off, 64));
            float e = expf(arg-mx);
            float ssum = e;
#pragma unroll
            for (int off=8; off>=1; off>>=1) ssum += __shfl_xor(ssum, off, 64);
            r = (e/ssum)*av;
        }
        racc += r;
#pragma unroll
        for (int d=0;d<16;d++){
            s1[d] = fmaf(r, V[d], s1[d]);
            s2[d] = fmaf(r*V[d], V[d], s2[d]);
        }
    }

    float* pp = Part + (size_t)wg*33*256 + t;
    pp[0] = racc;
#pragma unroll
    for (int d=0;d<16;d++){
        pp[(size_t)(1+d)*256]  = s1[d];
        pp[(size_t)(17+d)*256] = s2[d];
    }
}

// ---------------- full reduce: 512 partials -> Red[33][256] ----------------
__global__ __launch_bounds__(256) void k_red(const float* __restrict__ Part,
    float* __restrict__ Red)
{
    const int k = blockIdx.x;   // 0..32
    const int t = threadIdx.x;
    const float* src = Part + (size_t)k*256 + t;
    float a0=0,a1=0,a2=0,a3=0,a4=0,a5=0,a6=0,a7=0;
    for (int i=0;i<512;i+=8){
        a0 += src[(size_t)(i+0)*8448];
        a1 += src[(size_t)(i+1)*8448];
        a2 += src[(size_t)(i+2)*8448];
        a3 += src[(size_t)(i+3)*8448];
        a4 += src[(size_t)(i+4)*8448];
        a5 += src[(size_t)(i+5)*8448];
        a6 += src[(size_t)(i+6)*8448];
        a7 += src[(size_t)(i+7)*8448];
    }
    Red[(size_t)k*256 + t] = ((a0+a1)+(a2+a3)) + ((a4+a5)+(a6+a7));
}

// ---------------- final: in-block derive + BN(m) per c + BN(a)+sigmoid ----------------
__global__ __launch_bounds__(256) void k_final(const float* __restrict__ RedG,
    const float* __restrict__ bu, const float* __restrict__ ba,
    float* __restrict__ out)
{
    const int c = blockIdx.x;
    const int t = threadIdx.x;
    __shared__ float shMj[256];   // [n][d]
    __shared__ float shEp[16], shEl[16];
    __shared__ float red[8];

    if (t < 16){
        const int cell = t*16 + c;   // (n=t, c)
        const float* rp = RedG + cell;
        float Rj  = rp[0];
        float kap = 1.f + Rj;
        float nuv = 17.f + Rj;
        float ik  = 1.f/kap;
        float El  = 11.090354888959125f;
#pragma unroll
        for (int d=0; d<16; d++){
            float S1 = rp[(size_t)(1+d)*256];
            float S2 = rp[(size_t)(17+d)*256];
            shMj[t*16+d] = S1*ik;
            float iPsi = 1.f + S2 - S1*S1*ik;
            El -= logf(iPsi);
        }
#pragma unroll
        for (int d=0; d<16; d++) El += digamma_f(0.5f*(nuv - (float)d));
        float asum = 0.f;
#pragma unroll
        for (int cc=0; cc<16; cc++) asum += 1.f + RedG[t*16+cc];
        shEp[t] = digamma_f(kap) - digamma_f(asum);
        shEl[t] = El;
    }
    __syncthreads();

    const int n = t>>4, d = t&15;
    float mv = shMj[n*16+d];
    float s = mv, q = mv*mv;
#pragma unroll
    for (int off=32; off>=1; off>>=1){
        s += __shfl_xor(s, off, 64);
        q += __shfl_xor(q, off, 64);
    }
    if ((t&63)==0){ red[t>>6]=s; red[4+(t>>6)]=q; }
    __syncthreads();
    float S = red[0]+red[1]+red[2]+red[3];
    float Q = red[4]+red[5]+red[6]+red[7];
    float mean = S*(1.f/256.f);
    float var  = Q*(1.f/256.f) - mean*mean;
    float rs   = rsqrtf(var + 1e-5f);
    out[256 + (size_t)(n*16+c)*16 + d] = (mv-mean)*rs;

    if (t < 16){
        const int nn = t;
        float Ep = shEp[nn], El = shEl[nn];
        float Hq = 22.703016531274762f - 0.5f*El;   // 0.5*D*ln(2*pi*e) - 0.5*Elnlam
        float araw = ba[c] - (expf(Ep)*Hq + bu[c]);
        float as = araw, aq = araw*araw;
        // reduce over 16 n-lanes: width 16 so off=8 exchanges halves (R5 fix)
#pragma unroll
        for (int off=8; off>=1; off>>=1){
            as += __shfl_xor(as, off, 16);
            aq += __shfl_xor(aq, off, 16);
        }
        float am  = as*(1.f/16.f);
        float av  = aq*(1.f/16.f) - am*am;
        float ars = rsqrtf(av + 1e-5f);
        float z = (araw-am)*ars;
        out[nn*16+c] = 1.f/(1.f+expf(-z));
    }
}

extern "C" void kernel_launch(void* const* d_in, const int* in_sizes, int n_in,
                              void* d_out, int out_size, void* d_ws, size_t ws_size,
                              hipStream_t stream)
{
    const float* x   = (const float*)d_in[0];
    const float* pw  = (const float*)d_in[1];
    const float* gp  = (const float*)d_in[2];
    const float* bp  = (const float*)d_in[3];
    const float* ga  = (const float*)d_in[4];
    const float* bb  = (const float*)d_in[5];
    const float* Wij = (const float*)d_in[6];
    const float* bu  = (const float*)d_in[7];
    const float* ba  = (const float*)d_in[8];
    float* out = (float*)d_out;
    float* ws  = (float*)d_ws;

    float* POSEraw = ws + F_POSE;
    float* WT      = ws + F_WT;
    float* ACTraw  = ws + F_ACT;
    float* Part    = ws + F_PART;
    float* Red     = ws + F_RED;
    float* StatP   = ws + F_STATP;
    float* StatA   = ws + F_STATA;
    float* bnp     = ws + F_BNP;

    k_main<<<1056, 256, 0, stream>>>(x, pw, Wij, POSEraw, ACTraw, WT, StatP, StatA);
    k_bnfin<<<1, 64, 0, stream>>>(StatP, StatA, gp, bp, ga, bb, bnp);

    k_pass<1><<<512, 256, 0, stream>>>(POSEraw, ACTraw, WT, bnp, Red, Part);
    k_red<<<33, 256, 0, stream>>>(Part, Red);
    k_pass<0><<<512, 256, 0, stream>>>(POSEraw, ACTraw, WT, bnp, Red, Part);
    k_red<<<33, 256, 0, stream>>>(Part, Red);
    k_pass<0><<<512, 256, 0, stream>>>(POSEraw, ACTraw, WT, bnp, Red, Part);
    k_red<<<33, 256, 0, stream>>>(Part, Red);

    k_final<<<16, 256, 0, stream>>>(Red, bu, ba, out);
}

// Round 8
// 204.327 us; speedup vs baseline: 1.3288x; 1.2589x over previous
//
#include <hip/hip_runtime.h>
#include <hip/hip_bf16.h>
#include <math.h>

// Problem constants
#define N_   16
#define A_   64
#define HW_  256
#define B_   32
#define C_   16
#define D_   16

// ws layout (floats) — ~34.9 MB
#define F_POSE  0u          // 2097152  POSEraw [b][s][n][pp]  (raw conv out, transposed)
#define F_WT    2097152u    // 2097152  WT [b][s][c*16+mj]
#define F_ACT   4194304u    // 131072   ACTraw [ch=b][n][s]    (raw conv out)
#define F_PART  4325376u    // 4325376  Part[512][33][256]
#define F_RED8  8650752u    // 67584    Red8[8][33][256]
#define F_STATP 8718336u    // 1024     per-(b,n) pose sum/sumsq
#define F_STATA 8719360u    // 1024     per-(ch,n) act sum/sumsq

__device__ __forceinline__ float digamma_f(float x){
    // valid for x >= ~1 (all call sites); shift to x>=8 then asymptotic
    float r = 0.f;
    while (x < 8.f){ r -= 1.f/x; x += 1.f; }
    float inv = 1.f/x, inv2 = inv*inv;
    float p = logf(x) - 0.5f*inv
            - inv2*(0.08333333333333333f - inv2*(0.008333333333333333f - inv2*0.003968253968253968f));
    return r + p;
}

__device__ __forceinline__ float sigmoid_f(float x){ return 1.f/(1.f+expf(-x)); }

// ---------------- K1: conv 1x1 (raw, transposed out, + BN stat partials) fused with W transpose ----
// blocks 0..543: conv (g = blk%34, n = blk/34); blocks 544..1055: W transpose.
__global__ __launch_bounds__(256) void k_main(const float* __restrict__ x,
    const float* __restrict__ pw, const float* __restrict__ W,
    float* __restrict__ POSEraw, float* __restrict__ ACTraw, float* __restrict__ WTo,
    float* __restrict__ StatP, float* __restrict__ StatA)
{
    __shared__ float sh[4096];
    const int blk = blockIdx.x;
    const int t = threadIdx.x;
    if (blk < 544){
        const int g = blk % 34, n = blk / 34;
        float* swl = sh;                 // 1024 floats of weights
        ((float4*)swl)[t] = ((const float4*)(pw + (size_t)g*1024))[t];
        __syncthreads();
        const float* xp = x + (size_t)n*16384 + t;
        float acc[16];
#pragma unroll
        for (int i=0;i<16;i++) acc[i]=0.f;
#pragma unroll 4
        for (int a=0;a<A_;a++){
            float xv = xp[(size_t)a*256];
#pragma unroll
            for (int oo=0;oo<16;oo++) acc[oo] = fmaf(xv, swl[oo*64+a], acc[oo]);
        }
        if (g < 32){
            // raw transposed store: POSEraw[b][s][n][pp]
            float* dst = POSEraw + (size_t)g*65536 + (size_t)t*256 + n*16;
#pragma unroll
            for (int i=0;i<4;i++){
                float4 v; v.x=acc[i*4+0]; v.y=acc[i*4+1]; v.z=acc[i*4+2]; v.w=acc[i*4+3];
                *(float4*)(dst + i*4) = v;
            }
            // per-(b,n) partial stats over 16 pp x 256 sites
            float sp=0.f, sq=0.f;
#pragma unroll
            for (int oo=0;oo<16;oo++){ sp += acc[oo]; sq = fmaf(acc[oo], acc[oo], sq); }
#pragma unroll
            for (int off=32; off>=1; off>>=1){
                sp += __shfl_xor(sp, off, 64);
                sq += __shfl_xor(sq, off, 64);
            }
            float* red = sh + 1024;
            if ((t&63)==0){ red[t>>6]=sp; red[4+(t>>6)]=sq; }
            __syncthreads();
            if (t==0){
                StatP[(size_t)(g*16+n)*2  ] = red[0]+red[1]+red[2]+red[3];
                StatP[(size_t)(g*16+n)*2+1] = red[4]+red[5]+red[6]+red[7];
            }
        } else {
            // raw act store: ACTraw[ch][n][s]
#pragma unroll
            for (int oo=0;oo<16;oo++){
                const int ch = (g-32)*16 + oo;
                ACTraw[(size_t)ch*4096 + (size_t)n*256 + t] = acc[oo];
            }
            // per-(ch,n) partial stats over 256 sites
            float* ared = sh + 1024;     // [16 ch][8]
            const int wid = t>>6;
#pragma unroll
            for (int oo=0;oo<16;oo++){
                float s = acc[oo], q = acc[oo]*acc[oo];
#pragma unroll
                for (int off=32; off>=1; off>>=1){
                    s += __shfl_xor(s, off, 64);
                    q += __shfl_xor(q, off, 64);
                }
                if ((t&63)==0){ ared[oo*8+wid]=s; ared[oo*8+4+wid]=q; }
            }
            __syncthreads();
            if (t<16){
                const int ch = (g-32)*16 + t;
                StatA[(size_t)(ch*16+t>15?0:0)] = 0.f; // (dead store removed below)
            }
            if (t<16){
                const int ch = (g-32)*16 + t;
                StatA[(size_t)(ch*16+n)*2  ] = ared[t*8+0]+ared[t*8+1]+ared[t*8+2]+ared[t*8+3];
                StatA[(size_t)(ch*16+n)*2+1] = ared[t*8+4]+ared[t*8+5]+ared[t*8+6]+ared[t*8+7];
            }
        }
    } else {
        // W transpose: [b][cmj][s] -> [b][s][cmj]
        const int q = blk - 544;
        const int b = q & 31, chunk = q >> 5;
        const int s0 = chunk*16;
        float* lw = sh;                  // 4096 floats
        const float* src = W + ((size_t)b*256 + t)*256 + s0;
        float4 v0 = ((const float4*)src)[0];
        float4 v1 = ((const float4*)src)[1];
        float4 v2 = ((const float4*)src)[2];
        float4 v3 = ((const float4*)src)[3];
        lw[ 0*256+t]=v0.x; lw[ 1*256+t]=v0.y; lw[ 2*256+t]=v0.z; lw[ 3*256+t]=v0.w;
        lw[ 4*256+t]=v1.x; lw[ 5*256+t]=v1.y; lw[ 6*256+t]=v1.z; lw[ 7*256+t]=v1.w;
        lw[ 8*256+t]=v2.x; lw[ 9*256+t]=v2.y; lw[10*256+t]=v2.z; lw[11*256+t]=v2.w;
        lw[12*256+t]=v3.x; lw[13*256+t]=v3.y; lw[14*256+t]=v3.z; lw[15*256+t]=v3.w;
        __syncthreads();
        float* dst = WTo + ((size_t)b*256 + s0)*256;
#pragma unroll
        for (int j=0;j<4;j++){
            int flat = j*1024 + t*4;
            *(float4*)(dst + flat) = *(const float4*)(lw + flat);
        }
    }
}

// ---------------- pass: BN-fold + E-step + moments; derive inlined (it>0) ----------------
// grid 512 = (b,chunk); 256 threads = (n,c) = cell t. FIRST=1: R=1/C.
template<int FIRST>
__global__ __launch_bounds__(256) void k_pass(const float* __restrict__ POSEraw,
    const float* __restrict__ ACTraw, const float* __restrict__ WT,
    const float* __restrict__ StatP, const float* __restrict__ StatA,
    const float* __restrict__ gp, const float* __restrict__ bp,
    const float* __restrict__ ga, const float* __restrict__ bb,
    const float* __restrict__ Red8, float* __restrict__ Part)
{
    const int wg = blockIdx.x;
    const int chunk = wg & 15, b = wg >> 4;
    const int s0 = chunk*16;
    const int t = threadIdx.x;
    const int n = t>>4, c = t&15;
    __shared__ float shP[5120];   // [si][n][pad20]  BN-applied poses
    __shared__ float shW[5120];   // [si][c][pad20]
    __shared__ float shA[256];    // [si*16+n]       sigmoided acts
    __shared__ float shBN[4];     // {pose sc, pose sh, act sc, act sh} for this b

    // ---- phase A: stage W (no BN needed) + compute this block's BN params ----
    {
        const float* wsrc = WT + ((size_t)b*256 + s0)*256;
#pragma unroll
        for (int j=0;j<4;j++){
            int flat = j*1024 + t*4;
            int si = flat>>8, rm = flat&255;
            int nn = rm>>4, p0 = rm&15;
            *(float4*)(shW + si*320 + nn*20 + p0) = *(const float4*)(wsrc+flat);
        }
        if (t < 32){
            const bool isP = (t < 16);
            const int lane = t & 15;
            float S, Q;
            if (isP){ S = StatP[(size_t)(b*16+lane)*2]; Q = StatP[(size_t)(b*16+lane)*2+1]; }
            else    { S = StatA[(size_t)(b*16+lane)*2]; Q = StatA[(size_t)(b*16+lane)*2+1]; }
#pragma unroll
            for (int off=8; off>=1; off>>=1){
                S += __shfl_xor(S, off, 16);
                Q += __shfl_xor(Q, off, 16);
            }
            if (lane == 0){
                if (isP){
                    float mean = S*(1.f/65536.f), var = Q*(1.f/65536.f) - mean*mean;
                    float sc = gp[b]*rsqrtf(var + 1e-5f);
                    shBN[0] = sc; shBN[1] = bp[b] - mean*sc;
                } else {
                    float mean = S*(1.f/4096.f), var = Q*(1.f/4096.f) - mean*mean;
                    float sc = ga[b]*rsqrtf(var + 1e-5f);
                    shBN[2] = sc; shBN[3] = bb[b] - mean*sc;
                }
            }
        }
    }
    __syncthreads();

    // ---- phase B: stage POSE with BN + ACT with BN+sigmoid ----
    {
        const float sc = shBN[0], shf = shBN[1];
        const float* psrc = POSEraw + ((size_t)b*256 + s0)*256;
#pragma unroll
        for (int j=0;j<4;j++){
            int flat = j*1024 + t*4;
            int si = flat>>8, rm = flat&255;
            int nn = rm>>4, p0 = rm&15;
            float4 v = *(const float4*)(psrc+flat);
            v.x = fmaf(v.x, sc, shf); v.y = fmaf(v.y, sc, shf);
            v.z = fmaf(v.z, sc, shf); v.w = fmaf(v.w, sc, shf);
            *(float4*)(shP + si*320 + nn*20 + p0) = v;
        }
        if (t < 64){
            const float sa = shBN[2], ha = shBN[3];
            int nn = t>>2, s4 = (t&3)*4;
            float4 v = *(const float4*)(ACTraw + (size_t)b*4096 + nn*256 + s0 + s4);
            shA[(s4+0)*16+nn] = sigmoid_f(fmaf(v.x,sa,ha));
            shA[(s4+1)*16+nn] = sigmoid_f(fmaf(v.y,sa,ha));
            shA[(s4+2)*16+nn] = sigmoid_f(fmaf(v.z,sa,ha));
            shA[(s4+3)*16+nn] = sigmoid_f(fmaf(v.w,sa,ha));
        }
    }

    // ---- inline derive of this thread's (n,c) cell: 8-way fold of Red8 ----
    float mj[16], ip[16], basev=0.f, nuv=0.f;
    if (!FIRST){
        const float* rp = Red8 + t;
        float Rj = 0.f;
#pragma unroll
        for (int q=0;q<8;q++) Rj += rp[(size_t)(q*33)*256];
        float kap = 1.f + Rj;
        nuv = 17.f + Rj;
        float ik  = 1.f/kap;
        float El  = 11.090354888959125f;   // D*ln2
#pragma unroll
        for (int d=0; d<16; d++){
            float S1 = 0.f, S2 = 0.f;
#pragma unroll
            for (int q=0;q<8;q++){
                S1 += rp[(size_t)(q*33+1+d)*256];
                S2 += rp[(size_t)(q*33+17+d)*256];
            }
            mj[d] = S1*ik;
            float iPsi = 1.f + S2 - S1*S1*ik;
            ip[d] = 1.f/iPsi;
            El -= logf(iPsi);
        }
#pragma unroll
        for (int d=0; d<16; d++) El += digamma_f(0.5f*(nuv - (float)d));
        float asum = kap;
#pragma unroll
        for (int off=8; off>=1; off>>=1) asum += __shfl_xor(asum, off, 16);
        float Epi = digamma_f(kap) - digamma_f(asum);
        basev = Epi + 0.5f*El - 14.703016531274762f - 8.f*ik;
    }
    __syncthreads();

    float racc=0.f, s1[16], s2[16];
#pragma unroll
    for (int d=0;d<16;d++){ s1[d]=0.f; s2[d]=0.f; }

    for (int si=0; si<16; ++si){
        float P[16], Wv[16];
        const float* pb = shP + si*320 + n*20;
        const float* wb = shW + si*320 + c*20;
#pragma unroll
        for (int i=0;i<16;i+=4){
            float4 v = *(const float4*)(pb+i);
            P[i]=v.x; P[i+1]=v.y; P[i+2]=v.z; P[i+3]=v.w;
            float4 u = *(const float4*)(wb+i);
            Wv[i]=u.x; Wv[i+1]=u.y; Wv[i+2]=u.z; Wv[i+3]=u.w;
        }
        float V[16];
#pragma unroll
        for (int a=0;a<4;a++){
#pragma unroll
            for (int j=0;j<4;j++){
                float acc = P[a*4+0]*Wv[0*4+j];
                acc = fmaf(P[a*4+1], Wv[1*4+j], acc);
                acc = fmaf(P[a*4+2], Wv[2*4+j], acc);
                acc = fmaf(P[a*4+3], Wv[3*4+j], acc);
                V[a*4+j] = acc;
            }
        }
        const float av = shA[si*16+n];
        float r;
        if (FIRST){
            r = 0.0625f * av;
        } else {
            float q = 0.f;
#pragma unroll
            for (int d=0;d<16;d++){
                float dv = V[d]-mj[d];
                q = fmaf(dv*ip[d], dv, q);
            }
            float arg = fmaf(-0.5f*nuv, q, basev);
            float mx = arg;
#pragma unroll
            for (int off=8; off>=1; off>>=1) mx = fmaxf(mx, __shfl_xor(mx, off, 64));
            float e = expf(arg-mx);
            float ssum = e;
#pragma unroll
            for (int off=8; off>=1; off>>=1) ssum += __shfl_xor(ssum, off, 64);
            r = (e/ssum)*av;
        }
        racc += r;
#pragma unroll
        for (int d=0;d<16;d++){
            s1[d] = fmaf(r, V[d], s1[d]);
            s2[d] = fmaf(r*V[d], V[d], s2[d]);
        }
    }

    float* pp = Part + (size_t)wg*33*256 + t;
    pp[0] = racc;
#pragma unroll
    for (int d=0;d<16;d++){
        pp[(size_t)(1+d)*256]  = s1[d];
        pp[(size_t)(17+d)*256] = s2[d];
    }
}

// ---------------- reduce stage 1: 512 partials -> Red8[8][33][256] (264 blocks) ----------------
__global__ __launch_bounds__(256) void k_red(const float* __restrict__ Part,
    float* __restrict__ Red8)
{
    const int k = blockIdx.x;   // 0..32
    const int q = blockIdx.y;   // 0..7
    const int t = threadIdx.x;
    const float* src = Part + (size_t)q*64*8448 + (size_t)k*256 + t;
    float a0=0,a1=0,a2=0,a3=0,a4=0,a5=0,a6=0,a7=0;
#pragma unroll
    for (int i=0;i<64;i+=8){
        a0 += src[(size_t)(i+0)*8448];
        a1 += src[(size_t)(i+1)*8448];
        a2 += src[(size_t)(i+2)*8448];
        a3 += src[(size_t)(i+3)*8448];
        a4 += src[(size_t)(i+4)*8448];
        a5 += src[(size_t)(i+5)*8448];
        a6 += src[(size_t)(i+6)*8448];
        a7 += src[(size_t)(i+7)*8448];
    }
    Red8[((size_t)q*33 + k)*256 + t] = ((a0+a1)+(a2+a3)) + ((a4+a5)+(a6+a7));
}

// ---------------- final: in-block derive (8-fold) + BN(m) per c + BN(a)+sigmoid ----------------
__global__ __launch_bounds__(256) void k_final(const float* __restrict__ Red8,
    const float* __restrict__ bu, const float* __restrict__ ba,
    float* __restrict__ out)
{
    const int c = blockIdx.x;
    const int t = threadIdx.x;
    __shared__ float shMj[256];   // [n][d]
    __shared__ float shEp[16], shEl[16];
    __shared__ float red[8];

    if (t < 16){
        const int cell = t*16 + c;   // (n=t, c)
        const float* rp = Red8 + cell;
        float Rj = 0.f;
#pragma unroll
        for (int q=0;q<8;q++) Rj += rp[(size_t)(q*33)*256];
        float kap = 1.f + Rj;
        float nuv = 17.f + Rj;
        float ik  = 1.f/kap;
        float El  = 11.090354888959125f;
#pragma unroll
        for (int d=0; d<16; d++){
            float S1 = 0.f, S2 = 0.f;
#pragma unroll
            for (int q=0;q<8;q++){
                S1 += rp[(size_t)(q*33+1+d)*256];
                S2 += rp[(size_t)(q*33+17+d)*256];
            }
            shMj[t*16+d] = S1*ik;
            float iPsi = 1.f + S2 - S1*S1*ik;
            El -= logf(iPsi);
        }
#pragma unroll
        for (int d=0; d<16; d++) El += digamma_f(0.5f*(nuv - (float)d));
        float asum = 16.f;
        for (int cc=0; cc<16; cc++){
#pragma unroll
            for (int q=0;q<8;q++) asum += Red8[(size_t)(q*33)*256 + t*16+cc];
        }
        shEp[t] = digamma_f(kap) - digamma_f(asum);
        shEl[t] = El;
    }
    __syncthreads();

    const int n = t>>4, d = t&15;
    float mv = shMj[n*16+d];
    float s = mv, q = mv*mv;
#pragma unroll
    for (int off=32; off>=1; off>>=1){
        s += __shfl_xor(s, off, 64);
        q += __shfl_xor(q, off, 64);
    }
    if ((t&63)==0){ red[t>>6]=s; red[4+(t>>6)]=q; }
    __syncthreads();
    float S = red[0]+red[1]+red[2]+red[3];
    float Q = red[4]+red[5]+red[6]+red[7];
    float mean = S*(1.f/256.f);
    float var  = Q*(1.f/256.f) - mean*mean;
    float rs   = rsqrtf(var + 1e-5f);
    out[256 + (size_t)(n*16+c)*16 + d] = (mv-mean)*rs;

    if (t < 16){
        const int nn = t;
        float Ep = shEp[nn], El = shEl[nn];
        float Hq = 22.703016531274762f - 0.5f*El;   // 0.5*D*ln(2*pi*e) - 0.5*Elnlam
        float araw = ba[c] - (expf(Ep)*Hq + bu[c]);
        float as = araw, aq = araw*araw;
        // reduce over 16 n-lanes: width 16 so off=8 exchanges halves (R5 fix)
#pragma unroll
        for (int off=8; off>=1; off>>=1){
            as += __shfl_xor(as, off, 16);
            aq += __shfl_xor(aq, off, 16);
        }
        float am  = as*(1.f/16.f);
        float av  = aq*(1.f/16.f) - am*am;
        float ars = rsqrtf(av + 1e-5f);
        float z = (araw-am)*ars;
        out[nn*16+c] = 1.f/(1.f+expf(-z));
    }
}

extern "C" void kernel_launch(void* const* d_in, const int* in_sizes, int n_in,
                              void* d_out, int out_size, void* d_ws, size_t ws_size,
                              hipStream_t stream)
{
    const float* x   = (const float*)d_in[0];
    const float* pw  = (const float*)d_in[1];
    const float* gp  = (const float*)d_in[2];
    const float* bp  = (const float*)d_in[3];
    const float* ga  = (const float*)d_in[4];
    const float* bb  = (const float*)d_in[5];
    const float* Wij = (const float*)d_in[6];
    const float* bu  = (const float*)d_in[7];
    const float* ba  = (const float*)d_in[8];
    float* out = (float*)d_out;
    float* ws  = (float*)d_ws;

    float* POSEraw = ws + F_POSE;
    float* WT      = ws + F_WT;
    float* ACTraw  = ws + F_ACT;
    float* Part    = ws + F_PART;
    float* Red8    = ws + F_RED8;
    float* StatP   = ws + F_STATP;
    float* StatA   = ws + F_STATA;

    k_main<<<1056, 256, 0, stream>>>(x, pw, Wij, POSEraw, ACTraw, WT, StatP, StatA);

    k_pass<1><<<512, 256, 0, stream>>>(POSEraw, ACTraw, WT, StatP, StatA, gp, bp, ga, bb, Red8, Part);
    k_red<<<dim3(33,8), 256, 0, stream>>>(Part, Red8);
    k_pass<0><<<512, 256, 0, stream>>>(POSEraw, ACTraw, WT, StatP, StatA, gp, bp, ga, bb, Red8, Part);
    k_red<<<dim3(33,8), 256, 0, stream>>>(Part, Red8);
    k_pass<0><<<512, 256, 0, stream>>>(POSEraw, ACTraw, WT, StatP, StatA, gp, bp, ga, bb, Red8, Part);
    k_red<<<dim3(33,8), 256, 0, stream>>>(Part, Red8);

    k_final<<<16, 256, 0, stream>>>(Red8, bu, ba, out);
}